// Round 9
// baseline (1660.888 us; speedup 1.0000x reference)
//
#include <hip/hip_runtime.h>
#include <hip/hip_fp16.h>

typedef _Float16 f16;
typedef _Float16 f16x8 __attribute__((ext_vector_type(8)));
typedef float f32x16 __attribute__((ext_vector_type(16)));

#define NEGV (-1e30f)

constexpr int D_    = 1024;   // K
constexpr int ROWS  = 32768;
constexpr int BM    = 64;
constexpr int BK    = 64;
constexpr int KT    = D_ / BK;      // 16
constexpr int NWG   = ROWS / BM;    // 512
constexpr int NTHR  = 256;

// ws layout:
//  [0,1MB)  f16 weights, flat MFMA fragments (1KB each): frag F = kt*64+kf*16+proj*4+n
//           at byte F*1024 + lane*16
//  [1MB,3MB) boundary floats: bound[g][2][4][128] (half0=Cb, half1=Zb), g in [0,512)
#define BOUND_OFF (1u << 20)

// ---------------- shared macros (used by tc_main and ablations) ----------------
#define DECL_COMMON                                                              \
  const int tid  = threadIdx.x;                                                  \
  const int w    = tid >> 6;                                                     \
  const int lane = tid & 63;                                                     \
  const int g    = blockIdx.x;                                                   \
  const long long R0 = (long long)g * BM;                                        \
  f32x16 acc[2][4];                                                              \
  _Pragma("unroll")                                                              \
  for (int i = 0; i < 2; ++i)                                                    \
    _Pragma("unroll")                                                            \
    for (int jq = 0; jq < 4; ++jq)                                               \
      _Pragma("unroll")                                                          \
      for (int e = 0; e < 16; ++e) acc[i][jq][e] = 0.f;                          \
  const int ar   = tid >> 2;                                                     \
  const int akq  = tid & 3;                                                      \
  const float* aptr = H + (R0 + ar) * D_ + akq * 16;                             \
  const int abase = ar * 128;                                                    \
  const int aswz  = (ar & 7) << 4;                                               \
  const int mrow  = lane & 31;                                                   \
  const int kq2   = (lane >> 5) * 16;                                            \
  const int axor  = (mrow & 7) << 4;                                             \
  const int arow0 = mrow * 128;                                                  \
  const int arow1 = arow0 + 4096;                                                \
  const unsigned char* wsB = ws + (size_t)w * 1024 + lane * 16;                  \
  float4 aregX[4], aregY[4];

#define LOAD_A(KTN, A)                                                           \
  { const float4* p = (const float4*)(aptr + (KTN) * 64);                        \
    A[0] = p[0]; A[1] = p[1]; A[2] = p[2]; A[3] = p[3]; }

#define WRITE_A(DSTOFF, A)                                                       \
  { f16x8 v0, v1; const float* af = (const float*)A;                             \
    _Pragma("unroll")                                                            \
    for (int e = 0; e < 8; ++e) { v0[e] = (f16)af[e]; v1[e] = (f16)af[8 + e]; }  \
    *(f16x8*)(lds + (DSTOFF) + abase + ((akq*32)      ^ aswz)) = v0;             \
    *(f16x8*)(lds + (DSTOFF) + abase + ((akq*32 + 16) ^ aswz)) = v1; }

#define MFMA8(A0, A1, B0, B1, B2, B3)                                            \
  { acc[0][0] = __builtin_amdgcn_mfma_f32_32x32x16_f16(A0, B0, acc[0][0], 0,0,0); \
    acc[1][0] = __builtin_amdgcn_mfma_f32_32x32x16_f16(A1, B0, acc[1][0], 0,0,0); \
    acc[0][1] = __builtin_amdgcn_mfma_f32_32x32x16_f16(A0, B1, acc[0][1], 0,0,0); \
    acc[1][1] = __builtin_amdgcn_mfma_f32_32x32x16_f16(A1, B1, acc[1][1], 0,0,0); \
    acc[0][2] = __builtin_amdgcn_mfma_f32_32x32x16_f16(A0, B2, acc[0][2], 0,0,0); \
    acc[1][2] = __builtin_amdgcn_mfma_f32_32x32x16_f16(A1, B2, acc[1][2], 0,0,0); \
    acc[0][3] = __builtin_amdgcn_mfma_f32_32x32x16_f16(A0, B3, acc[0][3], 0,0,0); \
    acc[1][3] = __builtin_amdgcn_mfma_f32_32x32x16_f16(A1, B3, acc[1][3], 0,0,0); }

#define COMPUTE(SAOFF, KTc)                                                      \
  { _Pragma("unroll")                                                            \
    for (int kf = 0; kf < 4; ++kf) {                                             \
      const unsigned char* bp = wsB + (size_t)((KTc)*64 + kf*16) * 1024;         \
      f16x8 b0 = *(const f16x8*)(bp);                                            \
      f16x8 b1 = *(const f16x8*)(bp + 4096);                                     \
      f16x8 b2 = *(const f16x8*)(bp + 8192);                                     \
      f16x8 b3 = *(const f16x8*)(bp + 12288);                                    \
      const int ko = ((kf*32 + kq2) ^ axor);                                     \
      f16x8 a0 = *(const f16x8*)(lds + (SAOFF) + arow0 + ko);                    \
      f16x8 a1 = *(const f16x8*)(lds + (SAOFF) + arow1 + ko);                    \
      MFMA8(a0, a1, b0, b1, b2, b3) } }

#define COMPUTE_NOB(SAOFF)                                                       \
  { _Pragma("unroll")                                                            \
    for (int kf = 0; kf < 4; ++kf) {                                             \
      const int ko = ((kf*32 + kq2) ^ axor);                                     \
      f16x8 a0 = *(const f16x8*)(lds + (SAOFF) + arow0 + ko);                    \
      f16x8 a1 = *(const f16x8*)(lds + (SAOFF) + arow1 + ko);                    \
      MFMA8(a0, a1, cb0, cb1, cb2, cb3) } }

#define STEP_TAIL()                                                              \
  __builtin_amdgcn_sched_barrier(0);                                             \
  asm volatile("s_waitcnt lgkmcnt(0)" ::: "memory");                             \
  __builtin_amdgcn_sched_barrier(0);                                             \
  __builtin_amdgcn_s_barrier();                                                  \
  __builtin_amdgcn_sched_barrier(0)

#define ABL_STORE()                                                              \
  { float* o = out + ((size_t)g * NTHR + tid) * 8;                               \
    _Pragma("unroll")                                                            \
    for (int e = 0; e < 8; ++e) {                                                \
      float v = 0.f;                                                             \
      _Pragma("unroll")                                                          \
      for (int i = 0; i < 2; ++i)                                                \
        _Pragma("unroll")                                                        \
        for (int jq = 0; jq < 4; ++jq) v += acc[i][jq][e] + acc[i][jq][e + 8];   \
      o[e] = v; } }

#define CONST_F16(NAME, SALT)                                                    \
  f16x8 NAME;                                                                    \
  _Pragma("unroll")                                                              \
  for (int e = 0; e < 8; ++e) NAME[e] = (f16)(float)(1 + ((lane + e + (SALT)) & 3));

// ---------------- prep: weight fragment layout, boundary rows ----------------
__global__ __launch_bounds__(1024) void tc_prep(
    const float* __restrict__ H,
    const float* __restrict__ Wakv, const float* __restrict__ Wbkv,
    const float* __restrict__ Waz,  const float* __restrict__ Wbz,
    unsigned char* __restrict__ ws)
{
  const int b = blockIdx.x, t = threadIdx.x;
  if (b < NWG) {
    float* bound = (float*)(ws + BOUND_OFF) + (long long)b * 1024;
    if ((b & 127) == 0) {
      bound[t] = (t < 512) ? 0.f : NEGV;
      return;
    }
    __shared__ float hrow[4][1024];
    __shared__ float part[8][8][128];
    const long long R0 = (long long)b * BM - 4;
    for (int i = t; i < 4096; i += 1024) hrow[i >> 10][i & 1023] = H[R0 * D_ + i];
    __syncthreads();
    const int j  = t & 127;
    const int kc = t >> 7;
    const int k0 = kc * 128;
    float acc[2][4] = {{0.f,0.f,0.f,0.f},{0.f,0.f,0.f,0.f}};
#pragma unroll 4
    for (int k = k0; k < k0 + 128; ++k) {
      const float w0 = Wbkv[k*128 + j];
      const float w1 = Wbz [k*128 + j];
#pragma unroll
      for (int m = 0; m < 4; ++m) {
        const float hv = hrow[m][k];
        acc[0][m] += hv * w0;
        acc[1][m] += hv * w1;
      }
    }
#pragma unroll
    for (int half = 0; half < 2; ++half)
#pragma unroll
      for (int m = 0; m < 4; ++m) part[kc][half*4 + m][j] = acc[half][m];
    __syncthreads();
    {
      const int half = t >> 9, rm = (t >> 7) & 3, jj = t & 127;
      float s = 0.f;
#pragma unroll
      for (int kk = 0; kk < 8; ++kk) s += part[kk][half*4 + rm][jj];
      bound[t] = s;
    }
  } else {
    const int u    = (b - NWG) * 1024 + t;
    const int l    = u & 63;
    const int f    = u >> 6;
    const int n    = f & 3;
    const int proj = (f >> 2) & 3;
    const int kf   = (f >> 4) & 3;
    const int kt   = f >> 6;
    const float* Wm = (proj == 0) ? Wakv : (proj == 1) ? Wbkv : (proj == 2) ? Waz : Wbz;
    const int kb = kt*64 + kf*16 + (l >> 5)*8;
    const int j  = n*32 + (l & 31);
    f16x8 v;
#pragma unroll
    for (int e = 0; e < 8; ++e) v[e] = (f16)Wm[(kb + e)*128 + j];
    *(f16x8*)(ws + (size_t)u * 16) = v;
  }
}

// ================= ablation kernels (outputs overwritten by tc_main) =========
__global__ __launch_bounds__(NTHR, 2) void abl_skel(
    const float* __restrict__ H, const unsigned char* __restrict__ ws,
    float* __restrict__ out)
{
  __shared__ __align__(16) unsigned char lds[65536];
  DECL_COMMON
  LOAD_A(0, aregX); WRITE_A(0, aregX); LOAD_A(1, aregX); STEP_TAIL();
  for (int rep = 0; rep < 4; ++rep)
    for (int kt = 0; kt < KT; kt += 2) {
      LOAD_A((kt + 2) & (KT - 1), aregY);
      COMPUTE(0, kt);
      WRITE_A(8192, aregX);
      STEP_TAIL();
      LOAD_A((kt + 3) & (KT - 1), aregX);
      COMPUTE(8192, kt + 1);
      WRITE_A(0, aregY);
      STEP_TAIL();
    }
  ABL_STORE()
}

__global__ __launch_bounds__(NTHR, 2) void abl_nosync(
    const float* __restrict__ H, const unsigned char* __restrict__ ws,
    float* __restrict__ out)
{
  __shared__ __align__(16) unsigned char lds[65536];
  DECL_COMMON
  LOAD_A(0, aregX); WRITE_A(0, aregX); LOAD_A(1, aregX);
  for (int rep = 0; rep < 4; ++rep)
    for (int kt = 0; kt < KT; kt += 2) {
      LOAD_A((kt + 2) & (KT - 1), aregY);
      COMPUTE(0, kt);
      WRITE_A(8192, aregX);
      LOAD_A((kt + 3) & (KT - 1), aregX);
      COMPUTE(8192, kt + 1);
      WRITE_A(0, aregY);
    }
  ABL_STORE()
}

__global__ __launch_bounds__(NTHR, 2) void abl_noB(
    const float* __restrict__ H, const unsigned char* __restrict__ ws,
    float* __restrict__ out)
{
  __shared__ __align__(16) unsigned char lds[65536];
  DECL_COMMON
  CONST_F16(cb0, 0) CONST_F16(cb1, 1) CONST_F16(cb2, 2) CONST_F16(cb3, 3)
  LOAD_A(0, aregX); WRITE_A(0, aregX); LOAD_A(1, aregX); STEP_TAIL();
  for (int rep = 0; rep < 4; ++rep)
    for (int kt = 0; kt < KT; kt += 2) {
      LOAD_A((kt + 2) & (KT - 1), aregY);
      COMPUTE_NOB(0);
      WRITE_A(8192, aregX);
      STEP_TAIL();
      LOAD_A((kt + 3) & (KT - 1), aregX);
      COMPUTE_NOB(8192);
      WRITE_A(0, aregY);
      STEP_TAIL();
    }
  ABL_STORE()
}

__global__ __launch_bounds__(NTHR, 2) void abl_noA(
    const float* __restrict__ H, const unsigned char* __restrict__ ws,
    float* __restrict__ out)
{
  __shared__ __align__(16) unsigned char lds[65536];
  DECL_COMMON
  CONST_F16(wc0, 4) CONST_F16(wc1, 5)
  (void)aptr; (void)aregX; (void)aregY;
#define WRITE_RAW(DSTOFF)                                                        \
  { *(f16x8*)(lds + (DSTOFF) + abase + ((akq*32)      ^ aswz)) = wc0;            \
    *(f16x8*)(lds + (DSTOFF) + abase + ((akq*32 + 16) ^ aswz)) = wc1; }
  WRITE_RAW(0); STEP_TAIL();
  for (int rep = 0; rep < 4; ++rep)
    for (int kt = 0; kt < KT; kt += 2) {
      COMPUTE(0, kt);
      WRITE_RAW(8192);
      STEP_TAIL();
      COMPUTE(8192, kt + 1);
      WRITE_RAW(0);
      STEP_TAIL();
    }
  ABL_STORE()
}

__global__ __launch_bounds__(NTHR, 2) void abl_mfma(float* __restrict__ out)
{
  __shared__ __align__(16) unsigned char lds[65536];
  const int tid = threadIdx.x, lane = tid & 63, g = blockIdx.x;
  *(int*)(lds + tid * 4) = tid;   // keep LDS allocated (occupancy parity)
  CONST_F16(ca0, 0) CONST_F16(ca1, 1)
  CONST_F16(cb0, 2) CONST_F16(cb1, 3) CONST_F16(cb2, 4) CONST_F16(cb3, 5)
  f32x16 acc[2][4];
#pragma unroll
  for (int i = 0; i < 2; ++i)
#pragma unroll
    for (int jq = 0; jq < 4; ++jq)
#pragma unroll
      for (int e = 0; e < 16; ++e) acc[i][jq][e] = 0.f;
  for (int rep = 0; rep < 8; ++rep)
    for (int kt = 0; kt < KT; ++kt) {
#pragma unroll
      for (int kf = 0; kf < 4; ++kf) MFMA8(ca0, ca1, cb0, cb1, cb2, cb3)
    }
  ABL_STORE()
}

// ---------------- main fused kernel (IDENTICAL to R8) ----------------
__global__ __launch_bounds__(NTHR, 2) void tc_main(
    const float* __restrict__ H,
    const float* __restrict__ Ba,
    const float* __restrict__ Bbb,
    const unsigned char* __restrict__ ws,
    float* __restrict__ out)
{
  __shared__ __align__(16) unsigned char lds[65536];
  DECL_COMMON
  LOAD_A(0, aregX); WRITE_A(0, aregX); LOAD_A(1, aregX); STEP_TAIL();
  for (int kt = 0; kt < KT; kt += 2) {
    LOAD_A((kt + 2) & (KT - 1), aregY);
    COMPUTE(0, kt);
    WRITE_A(8192, aregX);
    STEP_TAIL();
    LOAD_A((kt + 3) & (KT - 1), aregX);
    COMPUTE(8192, kt + 1);
    WRITE_A(0, aregY);
    STEP_TAIL();
  }

  // ---------------- epilogue ----------------
  float* eCb = (float*)lds;
  float* eZb = (float*)(lds + 32768);
  const int jj = w*32 + mrow;
  const int h  = lane >> 5;

#pragma unroll
  for (int rf = 0; rf < 2; ++rf)
#pragma unroll
    for (int r = 0; r < 16; ++r) {
      const int row = rf*32 + (r & 3) + 8*(r >> 2) + 4*h;
      eCb[row*128 + jj] = acc[rf][1][r];
      eZb[row*128 + jj] = acc[rf][3][r];
    }
  __syncthreads();

  float bav[4], bbv[4];
#pragma unroll
  for (int m = 0; m < 4; ++m) { bav[m] = Ba[m*128 + jj]; bbv[m] = Bbb[m*128 + jj]; }
  const float* bound = (const float*)(ws + BOUND_OFF) + (long long)g * 1024;

#pragma unroll
  for (int rf = 0; rf < 2; ++rf)
#pragma unroll
    for (int q = 0; q < 4; ++q) {
      const int bl = rf*8 + 2*q + h;
      float za[4], ca[4], zb[4], cb[4];
#pragma unroll
      for (int m = 0; m < 4; ++m) {
        za[m] = acc[rf][2][q*4 + m] + bav[m];
        ca[m] = acc[rf][0][q*4 + m];
      }
      if (bl == 0) {
#pragma unroll
        for (int m = 0; m < 4; ++m) {
          cb[m] = bound[m*128 + jj];
          zb[m] = bound[512 + m*128 + jj] + bbv[m];
        }
      } else {
#pragma unroll
        for (int m = 0; m < 4; ++m) {
          const int pr = bl*4 - 4 + m;
          cb[m] = eCb[pr*128 + jj];
          zb[m] = eZb[pr*128 + jj] + bbv[m];
        }
      }
      float mx = za[0];
#pragma unroll
      for (int m = 1; m < 4; ++m) mx = fmaxf(mx, za[m]);
#pragma unroll
      for (int m = 0; m < 4; ++m) mx = fmaxf(mx, zb[m]);
      float s = 0.f, o = 0.f;
#pragma unroll
      for (int m = 0; m < 4; ++m) {
        const float ea = __expf(za[m] - mx);
        const float eb = __expf(zb[m] - mx);
        s += ea + eb;
        o += ea*ca[m] + eb*cb[m];
      }
      out[((long long)g*16 + bl)*128 + jj] = o / s;
    }
}

extern "C" void kernel_launch(void* const* d_in, const int* in_sizes, int n_in,
                              void* d_out, int out_size, void* d_ws, size_t ws_size,
                              hipStream_t stream) {
  const float* H    = (const float*)d_in[0];
  const float* Wakv = (const float*)d_in[1];
  const float* Wbkv = (const float*)d_in[2];
  const float* Waz  = (const float*)d_in[3];
  const float* Wbz  = (const float*)d_in[4];
  const float* Ba   = (const float*)d_in[5];
  const float* Bbb  = (const float*)d_in[6];
  float* out        = (float*)d_out;
  unsigned char* ws = (unsigned char*)d_ws;

  tc_prep<<<NWG + 64, 1024, 0, stream>>>(H, Wakv, Wbkv, Waz, Wbz, ws);
  // ablation probes (write to out; tc_main fully overwrites out afterwards)
  abl_mfma  <<<NWG, NTHR, 0, stream>>>(out);
  abl_noB   <<<NWG, NTHR, 0, stream>>>(H, ws, out);
  abl_noA   <<<NWG, NTHR, 0, stream>>>(H, ws, out);
  abl_nosync<<<NWG, NTHR, 0, stream>>>(H, ws, out);
  abl_skel  <<<NWG, NTHR, 0, stream>>>(H, ws, out);
  tc_main<<<NWG, NTHR, 0, stream>>>(H, Ba, Bbb, ws, out);
}

// Round 10
// 82.424 us; speedup vs baseline: 20.1505x; 20.1505x over previous
//
#include <hip/hip_runtime.h>
#include <hip/hip_fp16.h>

typedef _Float16 f16;
typedef _Float16 f16x8 __attribute__((ext_vector_type(8)));
typedef float f32x16 __attribute__((ext_vector_type(16)));

#define NEGV (-1e30f)

constexpr int D_    = 1024;   // K
constexpr int ROWS  = 32768;
constexpr int BM    = 64;
constexpr int BK    = 64;
constexpr int KT    = D_ / BK;      // 16
constexpr int NWG   = ROWS / BM;    // 512
constexpr int NTHR  = 256;

// ws layout:
//  [0,1MB)  f16 weights, flat MFMA fragments (1KB each): frag F = kt*64+kf*16+proj*4+n
//           at byte F*1024 + lane*16
//  [1MB,3MB) boundary floats: bound[g][2][4][128] (half0=Cb, half1=Zb), g in [0,512)
#define BOUND_OFF (1u << 20)

// ---------------- prep: weight fragment layout, boundary rows ----------------
__global__ __launch_bounds__(1024) void tc_prep(
    const float* __restrict__ H,
    const float* __restrict__ Wakv, const float* __restrict__ Wbkv,
    const float* __restrict__ Waz,  const float* __restrict__ Wbz,
    unsigned char* __restrict__ ws)
{
  const int b = blockIdx.x, t = threadIdx.x;
  if (b < NWG) {
    float* bound = (float*)(ws + BOUND_OFF) + (long long)b * 1024;
    if ((b & 127) == 0) {
      bound[t] = (t < 512) ? 0.f : NEGV;
      return;
    }
    __shared__ float hrow[4][1024];
    __shared__ float part[8][8][128];
    const long long R0 = (long long)b * BM - 4;
    for (int i = t; i < 4096; i += 1024) hrow[i >> 10][i & 1023] = H[R0 * D_ + i];
    __syncthreads();
    const int j  = t & 127;
    const int kc = t >> 7;
    const int k0 = kc * 128;
    float acc[2][4] = {{0.f,0.f,0.f,0.f},{0.f,0.f,0.f,0.f}};
#pragma unroll 4
    for (int k = k0; k < k0 + 128; ++k) {
      const float w0 = Wbkv[k*128 + j];
      const float w1 = Wbz [k*128 + j];
#pragma unroll
      for (int m = 0; m < 4; ++m) {
        const float hv = hrow[m][k];
        acc[0][m] += hv * w0;
        acc[1][m] += hv * w1;
      }
    }
#pragma unroll
    for (int half = 0; half < 2; ++half)
#pragma unroll
      for (int m = 0; m < 4; ++m) part[kc][half*4 + m][j] = acc[half][m];
    __syncthreads();
    {
      const int half = t >> 9, rm = (t >> 7) & 3, jj = t & 127;
      float s = 0.f;
#pragma unroll
      for (int kk = 0; kk < 8; ++kk) s += part[kk][half*4 + rm][jj];
      bound[t] = s;
    }
  } else {
    const int u    = (b - NWG) * 1024 + t;
    const int l    = u & 63;
    const int f    = u >> 6;
    const int n    = f & 3;
    const int proj = (f >> 2) & 3;
    const int kf   = (f >> 4) & 3;
    const int kt   = f >> 6;
    const float* Wm = (proj == 0) ? Wakv : (proj == 1) ? Wbkv : (proj == 2) ? Waz : Wbz;
    const int kb = kt*64 + kf*16 + (l >> 5)*8;
    const int j  = n*32 + (l & 31);
    f16x8 v;
#pragma unroll
    for (int e = 0; e < 8; ++e) v[e] = (f16)Wm[(kb + e)*128 + j];
    *(f16x8*)(ws + (size_t)u * 16) = v;
  }
}

// ---------------- main fused kernel ----------------
// BM=64, 4 waves, 2 blocks/CU. A via 16KB dbuf LDS (reg-staged, 1-step prefetch);
// B: ALL 16 fragments batch-loaded global->VGPR at step top (single latency
// window per step instead of 4 serialized ones).
__global__ __launch_bounds__(NTHR, 2) void tc_main(
    const float* __restrict__ H,
    const float* __restrict__ Ba,
    const float* __restrict__ Bbb,
    const unsigned char* __restrict__ ws,
    float* __restrict__ out)
{
  __shared__ __align__(16) unsigned char lds[65536];   // A0 8K | A1 8K | (epilogue 64K)

  const int tid  = threadIdx.x;
  const int w    = tid >> 6;
  const int lane = tid & 63;
  const int g    = blockIdx.x;
  const long long R0 = (long long)g * BM;

  f32x16 acc[2][4];
#pragma unroll
  for (int i = 0; i < 2; ++i)
#pragma unroll
    for (int jq = 0; jq < 4; ++jq)
#pragma unroll
      for (int e = 0; e < 16; ++e) acc[i][jq][e] = 0.f;

  // --- A staging: thread t -> row t>>2, 16-float chunk t&3
  const int ar   = tid >> 2;          // 0..63
  const int akq  = tid & 3;
  const float* aptr = H + (R0 + ar) * D_ + akq * 16;
  const int abase = ar * 128;
  const int aswz  = (ar & 7) << 4;

  // --- compute constants
  const int mrow  = lane & 31;
  const int kq2   = (lane >> 5) * 16;
  const int axor  = (mrow & 7) << 4;
  const int arow0 = mrow * 128;
  const int arow1 = arow0 + 4096;
  // B fragment (kt,kf,proj,n=w): byte = (kt*64+kf*16+proj*4+w)*1024 + lane*16
  const unsigned char* wsB = ws + (size_t)w * 1024 + lane * 16;

  float4 areg[4];

#define AOFF(IDX) ((IDX) * 8192)

#define LOAD_A(KTN)                                                              \
  { const float4* p = (const float4*)(aptr + (KTN) * 64);                        \
    areg[0] = p[0]; areg[1] = p[1]; areg[2] = p[2]; areg[3] = p[3]; }

#define WRITE_A(DSTOFF)                                                          \
  { f16x8 v0, v1; const float* af = (const float*)areg;                          \
    _Pragma("unroll")                                                            \
    for (int e = 0; e < 8; ++e) { v0[e] = (f16)af[e]; v1[e] = (f16)af[8 + e]; }  \
    *(f16x8*)(lds + (DSTOFF) + abase + ((akq*32)      ^ aswz)) = v0;             \
    *(f16x8*)(lds + (DSTOFF) + abase + ((akq*32 + 16) ^ aswz)) = v1; }

#define MFMA8(A0, A1, B0, B1, B2, B3)                                            \
  { acc[0][0] = __builtin_amdgcn_mfma_f32_32x32x16_f16(A0, B0, acc[0][0], 0,0,0); \
    acc[1][0] = __builtin_amdgcn_mfma_f32_32x32x16_f16(A1, B0, acc[1][0], 0,0,0); \
    acc[0][1] = __builtin_amdgcn_mfma_f32_32x32x16_f16(A0, B1, acc[0][1], 0,0,0); \
    acc[1][1] = __builtin_amdgcn_mfma_f32_32x32x16_f16(A1, B1, acc[1][1], 0,0,0); \
    acc[0][2] = __builtin_amdgcn_mfma_f32_32x32x16_f16(A0, B2, acc[0][2], 0,0,0); \
    acc[1][2] = __builtin_amdgcn_mfma_f32_32x32x16_f16(A1, B2, acc[1][2], 0,0,0); \
    acc[0][3] = __builtin_amdgcn_mfma_f32_32x32x16_f16(A0, B3, acc[0][3], 0,0,0); \
    acc[1][3] = __builtin_amdgcn_mfma_f32_32x32x16_f16(A1, B3, acc[1][3], 0,0,0); }

#define KF_BLOCK(SAOFF, KF, B0, B1, B2, B3)                                      \
  { const int ko = (((KF)*32 + kq2) ^ axor);                                     \
    f16x8 a0 = *(const f16x8*)(lds + (SAOFF) + arow0 + ko);                      \
    f16x8 a1 = *(const f16x8*)(lds + (SAOFF) + arow1 + ko);                      \
    MFMA8(a0, a1, B0, B1, B2, B3) }

#define STEP_TAIL()                                                              \
  __builtin_amdgcn_sched_barrier(0);                                             \
  asm volatile("s_waitcnt lgkmcnt(0)" ::: "memory");                             \
  __builtin_amdgcn_sched_barrier(0);                                             \
  __builtin_amdgcn_s_barrier();                                                  \
  __builtin_amdgcn_sched_barrier(0)

  // ---- prologue: stage A tile 0 ----
  LOAD_A(0);
  WRITE_A(AOFF(0));                 // compiler emits exact vmcnt wait for areg
  STEP_TAIL();

#pragma unroll 2
  for (int kt = 0; kt < KT; ++kt) {
    const int cur = kt & 1, nxt = cur ^ 1;
    const int saOff = AOFF(cur);
    // ---- batch: all 16 B fragment loads for step kt (one latency window) ----
    const unsigned char* bp = wsB + (size_t)kt * 65536;
    f16x8 b00 = *(const f16x8*)(bp);
    f16x8 b01 = *(const f16x8*)(bp +  4096);
    f16x8 b02 = *(const f16x8*)(bp +  8192);
    f16x8 b03 = *(const f16x8*)(bp + 12288);
    f16x8 b10 = *(const f16x8*)(bp + 16384);
    f16x8 b11 = *(const f16x8*)(bp + 20480);
    f16x8 b12 = *(const f16x8*)(bp + 24576);
    f16x8 b13 = *(const f16x8*)(bp + 28672);
    f16x8 b20 = *(const f16x8*)(bp + 32768);
    f16x8 b21 = *(const f16x8*)(bp + 36864);
    f16x8 b22 = *(const f16x8*)(bp + 40960);
    f16x8 b23 = *(const f16x8*)(bp + 45056);
    f16x8 b30 = *(const f16x8*)(bp + 49152);
    f16x8 b31 = *(const f16x8*)(bp + 53248);
    f16x8 b32 = *(const f16x8*)(bp + 57344);
    f16x8 b33 = *(const f16x8*)(bp + 61440);
    // A prefetch for tile kt+1 (consumed at WRITE_A below; full-step HBM cover)
    LOAD_A((kt + 1) & (KT - 1));
    // ---- consume per kf; compiler exact-counts vmcnt per group ----
    KF_BLOCK(saOff, 0, b00, b01, b02, b03);
    KF_BLOCK(saOff, 1, b10, b11, b12, b13);
    KF_BLOCK(saOff, 2, b20, b21, b22, b23);
    KF_BLOCK(saOff, 3, b30, b31, b32, b33);
    WRITE_A(AOFF(nxt));
    STEP_TAIL();
  }

  // ---------------- epilogue ----------------
  float* eCb = (float*)lds;               // [64][128]
  float* eZb = (float*)(lds + 32768);     // [64][128]
  const int jj = w*32 + mrow;             // channel 0..127
  const int h  = lane >> 5;

#pragma unroll
  for (int rf = 0; rf < 2; ++rf)
#pragma unroll
    for (int r = 0; r < 16; ++r) {
      const int row = rf*32 + (r & 3) + 8*(r >> 2) + 4*h;
      eCb[row*128 + jj] = acc[rf][1][r];
      eZb[row*128 + jj] = acc[rf][3][r];
    }
  __syncthreads();

  float bav[4], bbv[4];
#pragma unroll
  for (int m = 0; m < 4; ++m) { bav[m] = Ba[m*128 + jj]; bbv[m] = Bbb[m*128 + jj]; }
  const float* bound = (const float*)(ws + BOUND_OFF) + (long long)g * 1024;

#pragma unroll
  for (int rf = 0; rf < 2; ++rf)
#pragma unroll
    for (int q = 0; q < 4; ++q) {
      const int bl = rf*8 + 2*q + h;          // local M-block 0..15
      float za[4], ca[4], zb[4], cb[4];
#pragma unroll
      for (int m = 0; m < 4; ++m) {
        za[m] = acc[rf][2][q*4 + m] + bav[m];
        ca[m] = acc[rf][0][q*4 + m];
      }
      if (bl == 0) {
#pragma unroll
        for (int m = 0; m < 4; ++m) {
          cb[m] = bound[m*128 + jj];
          zb[m] = bound[512 + m*128 + jj] + bbv[m];
        }
      } else {
#pragma unroll
        for (int m = 0; m < 4; ++m) {
          const int pr = bl*4 - 4 + m;
          cb[m] = eCb[pr*128 + jj];
          zb[m] = eZb[pr*128 + jj] + bbv[m];
        }
      }
      float mx = za[0];
#pragma unroll
      for (int m = 1; m < 4; ++m) mx = fmaxf(mx, za[m]);
#pragma unroll
      for (int m = 0; m < 4; ++m) mx = fmaxf(mx, zb[m]);
      float s = 0.f, o = 0.f;
#pragma unroll
      for (int m = 0; m < 4; ++m) {
        const float ea = __expf(za[m] - mx);
        const float eb = __expf(zb[m] - mx);
        s += ea + eb;
        o += ea*ca[m] + eb*cb[m];
      }
      out[((long long)g*16 + bl)*128 + jj] = o / s;
    }
}

extern "C" void kernel_launch(void* const* d_in, const int* in_sizes, int n_in,
                              void* d_out, int out_size, void* d_ws, size_t ws_size,
                              hipStream_t stream) {
  const float* H    = (const float*)d_in[0];
  const float* Wakv = (const float*)d_in[1];
  const float* Wbkv = (const float*)d_in[2];
  const float* Waz  = (const float*)d_in[3];
  const float* Wbz  = (const float*)d_in[4];
  const float* Ba   = (const float*)d_in[5];
  const float* Bbb  = (const float*)d_in[6];
  float* out        = (float*)d_out;
  unsigned char* ws = (unsigned char*)d_ws;

  tc_prep<<<NWG + 64, 1024, 0, stream>>>(H, Wakv, Wbkv, Waz, Wbz, ws);
  tc_main<<<NWG, NTHR, 0, stream>>>(H, Ba, Bbb, ws, out);
}